// Round 20
// baseline (144.000 us; speedup 1.0000x reference)
//
#include <hip/hip_runtime.h>
#include <math.h>

#define N_PTS 512
#define HID 128
#define KNN 8
#define MT 16               // m-tile per block
#define NTHREADS 256        // 4 waves; each wave covers 2 g-tiles
#define NROWS 144           // 16 d rows + 128 a rows (8k x 16m)

typedef __attribute__((ext_vector_type(8))) short short8_t;   // 8 bf16 (4 VGPRs)
typedef __attribute__((ext_vector_type(4))) float f32x4_t;    // MFMA acc

// Persistent scratch in static device globals.
__device__ float g_refv[N_PTS * KNN * 3];          // [n][k][xyz] neighbor ref vectors
__device__ unsigned short g_wfrag[2 * 8 * 4 * 64 * 8]; // [sel][gtile][ktile][lane][j] bf16 B-frags

__device__ __forceinline__ unsigned short f2bf(float f) {   // RNE f32->bf16
    const unsigned int u = __float_as_uint(f);
    return (unsigned short)((u + 0x7FFFu + ((u >> 16) & 1u)) >> 16);
}

// -------- prep: fused wave-kNN + wfrag (VERBATIM r18/r19-PASS) --------------
__global__ void __launch_bounds__(64) prep_kernel(
    const float* __restrict__ points, const float* __restrict__ Wd,
    const float* __restrict__ Wa)
{
    __shared__ float spts[N_PTS * 3];
    const int lane = threadIdx.x;       // 0..63
    const int n = blockIdx.x;           // 0..511

    for (int i = lane; i < N_PTS * 3; i += 64) spts[i] = points[i];
    __syncthreads();

    // ---- weight fragments: this block converts 64 elements (512x64 = 32768) ----
    {
        const int idx = n * 64 + lane;
        const int sel = idx >> 14;          // 0 = Wd, 1 = Wa
        const int rem = idx & 16383;
        const int gg = rem >> 7, kk = rem & 127;
        const int gtile = gg >> 4, glo = gg & 15;
        const int ktile = kk >> 5, kmid = (kk >> 3) & 3, j = kk & 7;
        const int fl = kmid * 16 + glo;
        const int dst = ((((sel * 8 + gtile) * 4 + ktile) * 64) + fl) * 8 + j;
        const float v = sel ? Wa[gg * HID + kk] : Wd[gg * HID + kk];
        g_wfrag[dst] = f2bf(v);
    }

    // ---- kNN: 8 candidates per lane, 9 shfl-min rounds ----
    const float px = spts[n * 3 + 0], py = spts[n * 3 + 1], pz = spts[n * 3 + 2];
    unsigned long long keys[8];
#pragma unroll
    for (int j = 0; j < 8; ++j) {
        const int m = lane * 8 + j;
        const float dx = spts[m * 3 + 0] - px;
        const float dy = spts[m * 3 + 1] - py;
        const float dz = spts[m * 3 + 2] - pz;
        const float sq = dx * dx + dy * dy + dz * dz;
        keys[j] = ((unsigned long long)__float_as_uint(sq) << 32) | (unsigned)m;
    }
    // round 0 removes self (sq == +0 exactly); rounds 1..8 emit the 8 neighbors
    for (int r = 0; r < 9; ++r) {
        unsigned long long lmin = ~0ULL;
#pragma unroll
        for (int j = 0; j < 8; ++j) lmin = keys[j] < lmin ? keys[j] : lmin;
        for (int s = 1; s < 64; s <<= 1) {
            const unsigned long long o = __shfl_xor(lmin, s, 64);
            lmin = o < lmin ? o : lmin;
        }
        const int mwin = (int)(unsigned)lmin;
        if ((mwin >> 3) == lane) keys[mwin & 7] = ~0ULL;   // mark taken
        if (r > 0 && lane == 0) {
            const int k = r - 1;
            g_refv[(n * KNN + k) * 3 + 0] = __fsub_rn(spts[mwin * 3 + 0], px);
            g_refv[(n * KNN + k) * 3 + 1] = __fsub_rn(spts[mwin * 3 + 1], py);
            g_refv[(n * KNN + k) * 3 + 2] = __fsub_rn(spts[mwin * 3 + 2], pz);
        }
    }
}

// -------- main: r19 structure + hoisted B-frags + 4-waves/SIMD target -------
__global__ void __launch_bounds__(NTHREADS, 4) main_kernel(
    const float* __restrict__ points, const float* __restrict__ bd,
    const float* __restrict__ ba, float* __restrict__ out)
{
    __shared__ __align__(16) unsigned short sA[NROWS * HID];  // 36 KB bf16, XOR-swizzled
    __shared__ float sBase[NROWS];   // [0..15]=d_idx(m); [16+k*16+m]=a_idx(m,k)
    __shared__ float sRef[KNN][3];
    __shared__ float sPm[MT][3];
    __shared__ float sPn[3];

    const int t = threadIdx.x;
    const int n = blockIdx.y;
    const int m0 = blockIdx.x * MT;

    const int r0 = t >> 6;              // wave id (0..3) = row stripe
    const int i  = t & 63;              // frequency index (= lane)
    // per-thread frequency with 1/2pi folded: dv2 = 10000^(-i/64) / 2pi
    const float dv2 = expf(-0.14391156831212787f * (float)i) * 0.15915494309189535f;

    // ---- B-fragment loads HOISTED: L2 latency hides under geometry+fill ----
    const int wid  = r0;            // 0..3
    const int lane = i;
    const short8_t* wf = (const short8_t*)g_wfrag;
    short8_t wdb[2][4], wab[2][4];
#pragma unroll
    for (int gt = 0; gt < 2; ++gt) {
        const int gtile = wid * 2 + gt;
#pragma unroll
        for (int kt = 0; kt < 4; ++kt) {
            wdb[gt][kt] = wf[(gtile * 4 + kt) * 64 + lane];
            wab[gt][kt] = wf[((8 + gtile) * 4 + kt) * 64 + lane];
        }
    }

    // ---- stage small data ----
    if (t < 3) sPn[t] = points[n * 3 + t];
    if (t >= 64 && t < 64 + MT * 3) { int q = t - 64;  sPm[q / 3][q % 3] = points[m0 * 3 + q]; }
    if (t >= 128 && t < 128 + KNN * 3) { int q = t - 128; sRef[q / 3][q % 3] = g_refv[n * KNN * 3 + q]; }
    __syncthreads();

    // ---- geometry (r12-validated arithmetic, writes into flat sBase) ----
    if (t < MT) {
        const float qx = sPm[t][0], qy = sPm[t][1], qz = sPm[t][2];
        const float sn = __fadd_rn(__fadd_rn(__fmul_rn(sPn[0], sPn[0]), __fmul_rn(sPn[1], sPn[1])), __fmul_rn(sPn[2], sPn[2]));
        const float sm = __fadd_rn(__fadd_rn(__fmul_rn(qx, qx), __fmul_rn(qy, qy)), __fmul_rn(qz, qz));
        float dot = __fmul_rn(sPn[0], qx);
        dot = fmaf(sPn[1], qy, dot);
        dot = fmaf(sPn[2], qz, dot);
        float sq = __fsub_rn(__fadd_rn(sn, sm), __fadd_rn(dot, dot));
        sq = fmaxf(sq, 0.0f);
        sBase[t] = __fdiv_rn(__fsqrt_rn(sq), 0.2f);   // dist / SIGMA_D
    }
    if (t < MT * KNN) {
        const int pair = t >> 3, k = t & 7;
        const float ax = sPm[pair][0] - sPn[0];
        const float ay = sPm[pair][1] - sPn[1];
        const float az = sPm[pair][2] - sPn[2];
        const float rx = sRef[k][0], ry = sRef[k][1], rz = sRef[k][2];
        const float cx = ry * az - rz * ay;
        const float cy = rz * ax - rx * az;
        const float cz = rx * ay - ry * ax;
        const float sv = sqrtf(cx * cx + cy * cy + cz * cz);
        const float cv = rx * ax + ry * ay + rz * az;
        float ang;
        if (sv == 0.0f) ang = 0.0f;          // degenerate -> 0, NEVER pi (r12 fix)
        else            ang = atan2f(sv, cv);
        sBase[MT + k * 16 + pair] = ang * 3.8197186342054885f;   // * 180/(15*pi)
    }
    __syncthreads();

    // ---- A tile fill: thread = (freq i, stripe r0); rows r0+4*it, it<36 ----
    {
        const float* const rd = &sBase[r0];
        const unsigned base0 = (unsigned)((i * 4) ^ (r0 << 4)) + (unsigned)r0 * 256;
        char* const wr0 = (char*)sA + base0;          // even it (row&7 == r0)
        char* const wr1 = (char*)sA + (base0 ^ 64u);  // odd it  (row&7 == r0+4)
#pragma unroll
        for (int it = 0; it < 36; ++it) {
            const float base = rd[it * 4];                    // sBase[r0 + 4*it]
            const float rev0 = base * dv2;                    // radians->revs folded
            const float rev  = rev0 - floorf(rev0);           // v_fract: [0,1) revs
            const float s = __builtin_amdgcn_sinf(rev);
            const float c = __builtin_amdgcn_cosf(rev);
            const unsigned int pack = __builtin_amdgcn_perm(
                __float_as_uint(c), __float_as_uint(s), 0x07060302u);
            char* const wp = (it & 1) ? wr1 : wr0;
            *(unsigned int*)(wp + it * 1024) = pack;          // row*256 = r0*256 + it*1024
        }
    }
    __syncthreads();

    // ---- MFMA GEMM: wave w owns g-tiles {2w, 2w+1}; A-frag read ONCE -------
    const int rlo  = lane & 15;     // A row within tile / B col (g)
    const int kseg = lane >> 4;     // k sub-segment

    const char* sAb = (const char*)sA;
    f32x4_t accd[2] = {{0.f,0.f,0.f,0.f}, {0.f,0.f,0.f,0.f}};
#pragma unroll
    for (int kt = 0; kt < 4; ++kt) {
        int byte = rlo * 256 + kt * 64 + kseg * 16;
        byte ^= (rlo & 7) << 4;
        const short8_t af = *(const short8_t*)(sAb + byte);
        accd[0] = __builtin_amdgcn_mfma_f32_16x16x32_bf16(af, wdb[0][kt], accd[0], 0, 0, 0);
        accd[1] = __builtin_amdgcn_mfma_f32_16x16x32_bf16(af, wdb[1][kt], accd[1], 0, 0, 0);
    }

    f32x4_t amax[2] = {{0.f,0.f,0.f,0.f}, {0.f,0.f,0.f,0.f}};
#pragma unroll
    for (int k = 0; k < KNN; ++k) {
        f32x4_t acc0 = {0.f,0.f,0.f,0.f};
        f32x4_t acc1 = {0.f,0.f,0.f,0.f};
        const int rowb = MT + k * 16 + rlo;
#pragma unroll
        for (int kt = 0; kt < 4; ++kt) {
            int byte = rowb * 256 + kt * 64 + kseg * 16;
            byte ^= (rowb & 7) << 4;
            const short8_t af = *(const short8_t*)(sAb + byte);
            acc0 = __builtin_amdgcn_mfma_f32_16x16x32_bf16(af, wab[0][kt], acc0, 0, 0, 0);
            acc1 = __builtin_amdgcn_mfma_f32_16x16x32_bf16(af, wab[1][kt], acc1, 0, 0, 0);
        }
        if (k == 0) { amax[0] = acc0; amax[1] = acc1; }
        else {
#pragma unroll
            for (int r = 0; r < 4; ++r) {
                amax[0][r] = fmaxf(amax[0][r], acc0[r]);
                amax[1][r] = fmaxf(amax[1][r], acc1[r]);
            }
        }
    }

    // ---- epilogue: C/D mapping col=lane&15 (g), row=(lane>>4)*4+reg (m) ----
#pragma unroll
    for (int gt = 0; gt < 2; ++gt) {
        const int g = (wid * 2 + gt) * 16 + rlo;
        const float bdv = bd[g];
        const float bav = ba[g];
#pragma unroll
        for (int r = 0; r < 4; ++r) {
            const int m = m0 + kseg * 4 + r;
            out[(n * N_PTS + m) * HID + g] = accd[gt][r] + bdv + amax[gt][r] + bav;
        }
    }
}

extern "C" void kernel_launch(void* const* d_in, const int* in_sizes, int n_in,
                              void* d_out, int out_size, void* d_ws, size_t ws_size,
                              hipStream_t stream) {
    (void)in_sizes; (void)n_in; (void)out_size; (void)d_ws; (void)ws_size;
    const float* points = (const float*)d_in[0];
    const float* Wd     = (const float*)d_in[1];
    const float* bd     = (const float*)d_in[2];
    const float* Wa     = (const float*)d_in[3];
    const float* ba     = (const float*)d_in[4];
    float* out = (float*)d_out;

    prep_kernel<<<N_PTS, 64, 0, stream>>>(points, Wd, Wa);

    dim3 grid(N_PTS / MT, N_PTS);
    main_kernel<<<grid, NTHREADS, 0, stream>>>(points, bd, ba, out);
}

// Round 21
// 115.557 us; speedup vs baseline: 1.2461x; 1.2461x over previous
//
#include <hip/hip_runtime.h>
#include <math.h>

#define N_PTS 512
#define HID 128
#define KNN 8
#define MT 16               // m-tile per block
#define NTHREADS 256        // 4 waves; each wave covers 2 g-tiles
#define NROWS 144           // 16 d rows + 128 a rows (8k x 16m)

typedef __attribute__((ext_vector_type(8))) short short8_t;   // 8 bf16 (4 VGPRs)
typedef __attribute__((ext_vector_type(4))) float f32x4_t;    // MFMA acc

// Persistent scratch in static device globals.
__device__ float g_refv[N_PTS * KNN * 3];          // [n][k][xyz] neighbor ref vectors
__device__ unsigned short g_wfrag[2 * 8 * 4 * 64 * 8]; // [sel][gtile][ktile][lane][j] bf16 B-frags

__device__ __forceinline__ unsigned short f2bf(float f) {   // RNE f32->bf16
    const unsigned int u = __float_as_uint(f);
    return (unsigned short)((u + 0x7FFFu + ((u >> 16) & 1u)) >> 16);
}

// -------- prep: fused wave-kNN + wfrag (VERBATIM r18/r19-PASS) --------------
__global__ void __launch_bounds__(64) prep_kernel(
    const float* __restrict__ points, const float* __restrict__ Wd,
    const float* __restrict__ Wa)
{
    __shared__ float spts[N_PTS * 3];
    const int lane = threadIdx.x;       // 0..63
    const int n = blockIdx.x;           // 0..511

    for (int i = lane; i < N_PTS * 3; i += 64) spts[i] = points[i];
    __syncthreads();

    // ---- weight fragments: this block converts 64 elements (512x64 = 32768) ----
    {
        const int idx = n * 64 + lane;
        const int sel = idx >> 14;          // 0 = Wd, 1 = Wa
        const int rem = idx & 16383;
        const int gg = rem >> 7, kk = rem & 127;
        const int gtile = gg >> 4, glo = gg & 15;
        const int ktile = kk >> 5, kmid = (kk >> 3) & 3, j = kk & 7;
        const int fl = kmid * 16 + glo;
        const int dst = ((((sel * 8 + gtile) * 4 + ktile) * 64) + fl) * 8 + j;
        const float v = sel ? Wa[gg * HID + kk] : Wd[gg * HID + kk];
        g_wfrag[dst] = f2bf(v);
    }

    // ---- kNN: 8 candidates per lane, 9 shfl-min rounds ----
    const float px = spts[n * 3 + 0], py = spts[n * 3 + 1], pz = spts[n * 3 + 2];
    unsigned long long keys[8];
#pragma unroll
    for (int j = 0; j < 8; ++j) {
        const int m = lane * 8 + j;
        const float dx = spts[m * 3 + 0] - px;
        const float dy = spts[m * 3 + 1] - py;
        const float dz = spts[m * 3 + 2] - pz;
        const float sq = dx * dx + dy * dy + dz * dz;
        keys[j] = ((unsigned long long)__float_as_uint(sq) << 32) | (unsigned)m;
    }
    // round 0 removes self (sq == +0 exactly); rounds 1..8 emit the 8 neighbors
    for (int r = 0; r < 9; ++r) {
        unsigned long long lmin = ~0ULL;
#pragma unroll
        for (int j = 0; j < 8; ++j) lmin = keys[j] < lmin ? keys[j] : lmin;
        for (int s = 1; s < 64; s <<= 1) {
            const unsigned long long o = __shfl_xor(lmin, s, 64);
            lmin = o < lmin ? o : lmin;
        }
        const int mwin = (int)(unsigned)lmin;
        if ((mwin >> 3) == lane) keys[mwin & 7] = ~0ULL;   // mark taken
        if (r > 0 && lane == 0) {
            const int k = r - 1;
            g_refv[(n * KNN + k) * 3 + 0] = __fsub_rn(spts[mwin * 3 + 0], px);
            g_refv[(n * KNN + k) * 3 + 1] = __fsub_rn(spts[mwin * 3 + 1], py);
            g_refv[(n * KNN + k) * 3 + 2] = __fsub_rn(spts[mwin * 3 + 2], pz);
        }
    }
}

// -------- main: r19 structure + hoisted B-frags; launch_bounds (256,3) ------
// (r20's (256,4) forced a 64-VGPR budget -> spilled the hoisted frags to
//  scratch: +255 MB HBM writes, 113->144 us. VGPR cap at 3 waves/EU = 170
//  holds the ~124 live regs without spill.)
__global__ void __launch_bounds__(NTHREADS, 3) main_kernel(
    const float* __restrict__ points, const float* __restrict__ bd,
    const float* __restrict__ ba, float* __restrict__ out)
{
    __shared__ __align__(16) unsigned short sA[NROWS * HID];  // 36 KB bf16, XOR-swizzled
    __shared__ float sBase[NROWS];   // [0..15]=d_idx(m); [16+k*16+m]=a_idx(m,k)
    __shared__ float sRef[KNN][3];
    __shared__ float sPm[MT][3];
    __shared__ float sPn[3];

    const int t = threadIdx.x;
    const int n = blockIdx.y;
    const int m0 = blockIdx.x * MT;

    const int r0 = t >> 6;              // wave id (0..3) = row stripe
    const int i  = t & 63;              // frequency index (= lane)
    // per-thread frequency with 1/2pi folded: dv2 = 10000^(-i/64) / 2pi
    const float dv2 = expf(-0.14391156831212787f * (float)i) * 0.15915494309189535f;

    // ---- B-fragment loads HOISTED: L2 latency hides under geometry+fill ----
    const int wid  = r0;            // 0..3
    const int lane = i;
    const short8_t* wf = (const short8_t*)g_wfrag;
    short8_t wdb[2][4], wab[2][4];
#pragma unroll
    for (int gt = 0; gt < 2; ++gt) {
        const int gtile = wid * 2 + gt;
#pragma unroll
        for (int kt = 0; kt < 4; ++kt) {
            wdb[gt][kt] = wf[(gtile * 4 + kt) * 64 + lane];
            wab[gt][kt] = wf[((8 + gtile) * 4 + kt) * 64 + lane];
        }
    }

    // ---- stage small data ----
    if (t < 3) sPn[t] = points[n * 3 + t];
    if (t >= 64 && t < 64 + MT * 3) { int q = t - 64;  sPm[q / 3][q % 3] = points[m0 * 3 + q]; }
    if (t >= 128 && t < 128 + KNN * 3) { int q = t - 128; sRef[q / 3][q % 3] = g_refv[n * KNN * 3 + q]; }
    __syncthreads();

    // ---- geometry (r12-validated arithmetic, writes into flat sBase) ----
    if (t < MT) {
        const float qx = sPm[t][0], qy = sPm[t][1], qz = sPm[t][2];
        const float sn = __fadd_rn(__fadd_rn(__fmul_rn(sPn[0], sPn[0]), __fmul_rn(sPn[1], sPn[1])), __fmul_rn(sPn[2], sPn[2]));
        const float sm = __fadd_rn(__fadd_rn(__fmul_rn(qx, qx), __fmul_rn(qy, qy)), __fmul_rn(qz, qz));
        float dot = __fmul_rn(sPn[0], qx);
        dot = fmaf(sPn[1], qy, dot);
        dot = fmaf(sPn[2], qz, dot);
        float sq = __fsub_rn(__fadd_rn(sn, sm), __fadd_rn(dot, dot));
        sq = fmaxf(sq, 0.0f);
        sBase[t] = __fdiv_rn(__fsqrt_rn(sq), 0.2f);   // dist / SIGMA_D
    }
    if (t < MT * KNN) {
        const int pair = t >> 3, k = t & 7;
        const float ax = sPm[pair][0] - sPn[0];
        const float ay = sPm[pair][1] - sPn[1];
        const float az = sPm[pair][2] - sPn[2];
        const float rx = sRef[k][0], ry = sRef[k][1], rz = sRef[k][2];
        const float cx = ry * az - rz * ay;
        const float cy = rz * ax - rx * az;
        const float cz = rx * ay - ry * ax;
        const float sv = sqrtf(cx * cx + cy * cy + cz * cz);
        const float cv = rx * ax + ry * ay + rz * az;
        float ang;
        if (sv == 0.0f) ang = 0.0f;          // degenerate -> 0, NEVER pi (r12 fix)
        else            ang = atan2f(sv, cv);
        sBase[MT + k * 16 + pair] = ang * 3.8197186342054885f;   // * 180/(15*pi)
    }
    __syncthreads();

    // ---- A tile fill: thread = (freq i, stripe r0); rows r0+4*it, it<36 ----
    {
        const float* const rd = &sBase[r0];
        const unsigned base0 = (unsigned)((i * 4) ^ (r0 << 4)) + (unsigned)r0 * 256;
        char* const wr0 = (char*)sA + base0;          // even it (row&7 == r0)
        char* const wr1 = (char*)sA + (base0 ^ 64u);  // odd it  (row&7 == r0+4)
#pragma unroll
        for (int it = 0; it < 36; ++it) {
            const float base = rd[it * 4];                    // sBase[r0 + 4*it]
            const float rev0 = base * dv2;                    // radians->revs folded
            const float rev  = rev0 - floorf(rev0);           // v_fract: [0,1) revs
            const float s = __builtin_amdgcn_sinf(rev);
            const float c = __builtin_amdgcn_cosf(rev);
            const unsigned int pack = __builtin_amdgcn_perm(
                __float_as_uint(c), __float_as_uint(s), 0x07060302u);
            char* const wp = (it & 1) ? wr1 : wr0;
            *(unsigned int*)(wp + it * 1024) = pack;          // row*256 = r0*256 + it*1024
        }
    }
    __syncthreads();

    // ---- MFMA GEMM: wave w owns g-tiles {2w, 2w+1}; A-frag read ONCE -------
    const int rlo  = lane & 15;     // A row within tile / B col (g)
    const int kseg = lane >> 4;     // k sub-segment

    const char* sAb = (const char*)sA;
    f32x4_t accd[2] = {{0.f,0.f,0.f,0.f}, {0.f,0.f,0.f,0.f}};
#pragma unroll
    for (int kt = 0; kt < 4; ++kt) {
        int byte = rlo * 256 + kt * 64 + kseg * 16;
        byte ^= (rlo & 7) << 4;
        const short8_t af = *(const short8_t*)(sAb + byte);
        accd[0] = __builtin_amdgcn_mfma_f32_16x16x32_bf16(af, wdb[0][kt], accd[0], 0, 0, 0);
        accd[1] = __builtin_amdgcn_mfma_f32_16x16x32_bf16(af, wdb[1][kt], accd[1], 0, 0, 0);
    }

    f32x4_t amax[2] = {{0.f,0.f,0.f,0.f}, {0.f,0.f,0.f,0.f}};
#pragma unroll
    for (int k = 0; k < KNN; ++k) {
        f32x4_t acc0 = {0.f,0.f,0.f,0.f};
        f32x4_t acc1 = {0.f,0.f,0.f,0.f};
        const int rowb = MT + k * 16 + rlo;
#pragma unroll
        for (int kt = 0; kt < 4; ++kt) {
            int byte = rowb * 256 + kt * 64 + kseg * 16;
            byte ^= (rowb & 7) << 4;
            const short8_t af = *(const short8_t*)(sAb + byte);
            acc0 = __builtin_amdgcn_mfma_f32_16x16x32_bf16(af, wab[0][kt], acc0, 0, 0, 0);
            acc1 = __builtin_amdgcn_mfma_f32_16x16x32_bf16(af, wab[1][kt], acc1, 0, 0, 0);
        }
        if (k == 0) { amax[0] = acc0; amax[1] = acc1; }
        else {
#pragma unroll
            for (int r = 0; r < 4; ++r) {
                amax[0][r] = fmaxf(amax[0][r], acc0[r]);
                amax[1][r] = fmaxf(amax[1][r], acc1[r]);
            }
        }
    }

    // ---- epilogue: C/D mapping col=lane&15 (g), row=(lane>>4)*4+reg (m) ----
#pragma unroll
    for (int gt = 0; gt < 2; ++gt) {
        const int g = (wid * 2 + gt) * 16 + rlo;
        const float bdv = bd[g];
        const float bav = ba[g];
#pragma unroll
        for (int r = 0; r < 4; ++r) {
            const int m = m0 + kseg * 4 + r;
            out[(n * N_PTS + m) * HID + g] = accd[gt][r] + bdv + amax[gt][r] + bav;
        }
    }
}

extern "C" void kernel_launch(void* const* d_in, const int* in_sizes, int n_in,
                              void* d_out, int out_size, void* d_ws, size_t ws_size,
                              hipStream_t stream) {
    (void)in_sizes; (void)n_in; (void)out_size; (void)d_ws; (void)ws_size;
    const float* points = (const float*)d_in[0];
    const float* Wd     = (const float*)d_in[1];
    const float* bd     = (const float*)d_in[2];
    const float* Wa     = (const float*)d_in[3];
    const float* ba     = (const float*)d_in[4];
    float* out = (float*)d_out;

    prep_kernel<<<N_PTS, 64, 0, stream>>>(points, Wd, Wa);

    dim3 grid(N_PTS / MT, N_PTS);
    main_kernel<<<grid, NTHREADS, 0, stream>>>(points, bd, ba, out);
}

// Round 22
// 112.599 us; speedup vs baseline: 1.2789x; 1.0263x over previous
//
#include <hip/hip_runtime.h>
#include <math.h>

#define N_PTS 512
#define HID 128
#define KNN 8
#define MT 16               // m-tile per block
#define NTHREADS 256        // 4 waves; each wave covers 2 g-tiles
#define NROWS 144           // 16 d rows + 128 a rows (8k x 16m)

typedef __attribute__((ext_vector_type(8))) short short8_t;   // 8 bf16 (4 VGPRs)
typedef __attribute__((ext_vector_type(4))) float f32x4_t;    // MFMA acc

// Persistent scratch in static device globals.
__device__ float g_refv[N_PTS * KNN * 3];          // [n][k][xyz] neighbor ref vectors
__device__ unsigned short g_wfrag[2 * 8 * 4 * 64 * 8]; // [sel][gtile][ktile][lane][j] bf16 B-frags

__device__ __forceinline__ unsigned short f2bf(float f) {   // RNE f32->bf16
    const unsigned int u = __float_as_uint(f);
    return (unsigned short)((u + 0x7FFFu + ((u >> 16) & 1u)) >> 16);
}

// -------- prep: fused wave-kNN + wfrag (VERBATIM r18/r19-PASS) --------------
__global__ void __launch_bounds__(64) prep_kernel(
    const float* __restrict__ points, const float* __restrict__ Wd,
    const float* __restrict__ Wa)
{
    __shared__ float spts[N_PTS * 3];
    const int lane = threadIdx.x;       // 0..63
    const int n = blockIdx.x;           // 0..511

    for (int i = lane; i < N_PTS * 3; i += 64) spts[i] = points[i];
    __syncthreads();

    // ---- weight fragments: this block converts 64 elements (512x64 = 32768) ----
    {
        const int idx = n * 64 + lane;
        const int sel = idx >> 14;          // 0 = Wd, 1 = Wa
        const int rem = idx & 16383;
        const int gg = rem >> 7, kk = rem & 127;
        const int gtile = gg >> 4, glo = gg & 15;
        const int ktile = kk >> 5, kmid = (kk >> 3) & 3, j = kk & 7;
        const int fl = kmid * 16 + glo;
        const int dst = ((((sel * 8 + gtile) * 4 + ktile) * 64) + fl) * 8 + j;
        const float v = sel ? Wa[gg * HID + kk] : Wd[gg * HID + kk];
        g_wfrag[dst] = f2bf(v);
    }

    // ---- kNN: 8 candidates per lane, 9 shfl-min rounds ----
    const float px = spts[n * 3 + 0], py = spts[n * 3 + 1], pz = spts[n * 3 + 2];
    unsigned long long keys[8];
#pragma unroll
    for (int j = 0; j < 8; ++j) {
        const int m = lane * 8 + j;
        const float dx = spts[m * 3 + 0] - px;
        const float dy = spts[m * 3 + 1] - py;
        const float dz = spts[m * 3 + 2] - pz;
        const float sq = dx * dx + dy * dy + dz * dz;
        keys[j] = ((unsigned long long)__float_as_uint(sq) << 32) | (unsigned)m;
    }
    // round 0 removes self (sq == +0 exactly); rounds 1..8 emit the 8 neighbors
    for (int r = 0; r < 9; ++r) {
        unsigned long long lmin = ~0ULL;
#pragma unroll
        for (int j = 0; j < 8; ++j) lmin = keys[j] < lmin ? keys[j] : lmin;
        for (int s = 1; s < 64; s <<= 1) {
            const unsigned long long o = __shfl_xor(lmin, s, 64);
            lmin = o < lmin ? o : lmin;
        }
        const int mwin = (int)(unsigned)lmin;
        if ((mwin >> 3) == lane) keys[mwin & 7] = ~0ULL;   // mark taken
        if (r > 0 && lane == 0) {
            const int k = r - 1;
            g_refv[(n * KNN + k) * 3 + 0] = __fsub_rn(spts[mwin * 3 + 0], px);
            g_refv[(n * KNN + k) * 3 + 1] = __fsub_rn(spts[mwin * 3 + 1], py);
            g_refv[(n * KNN + k) * 3 + 2] = __fsub_rn(spts[mwin * 3 + 2], pz);
        }
    }
}

// -------- main: r19 structure (no hoist) + stripe-major sBase, batched reads -
__global__ void __launch_bounds__(NTHREADS, 3) main_kernel(
    const float* __restrict__ points, const float* __restrict__ bd,
    const float* __restrict__ ba, float* __restrict__ out)
{
    __shared__ __align__(16) unsigned short sA[NROWS * HID];  // 36 KB bf16, XOR-swizzled
    __shared__ __align__(16) float sBaseS[4][36];  // stripe-major: [row&3][row>>2]
    __shared__ float sRef[KNN][3];
    __shared__ float sPm[MT][3];
    __shared__ float sPn[3];

    const int t = threadIdx.x;
    const int n = blockIdx.y;
    const int m0 = blockIdx.x * MT;

    const int r0 = t >> 6;              // wave id (0..3) = row stripe
    const int i  = t & 63;              // frequency index (= lane)
    // per-thread frequency with 1/2pi folded: dv2 = 10000^(-i/64) / 2pi
    const float dv2 = expf(-0.14391156831212787f * (float)i) * 0.15915494309189535f;

    // ---- stage small data ----
    if (t < 3) sPn[t] = points[n * 3 + t];
    if (t >= 64 && t < 64 + MT * 3) { int q = t - 64;  sPm[q / 3][q % 3] = points[m0 * 3 + q]; }
    if (t >= 128 && t < 128 + KNN * 3) { int q = t - 128; sRef[q / 3][q % 3] = g_refv[n * KNN * 3 + q]; }
    __syncthreads();

    // ---- geometry (r12-validated arithmetic; row -> sBaseS[row&3][row>>2]) ----
    if (t < MT) {
        const float qx = sPm[t][0], qy = sPm[t][1], qz = sPm[t][2];
        const float sn = __fadd_rn(__fadd_rn(__fmul_rn(sPn[0], sPn[0]), __fmul_rn(sPn[1], sPn[1])), __fmul_rn(sPn[2], sPn[2]));
        const float sm = __fadd_rn(__fadd_rn(__fmul_rn(qx, qx), __fmul_rn(qy, qy)), __fmul_rn(qz, qz));
        float dot = __fmul_rn(sPn[0], qx);
        dot = fmaf(sPn[1], qy, dot);
        dot = fmaf(sPn[2], qz, dot);
        float sq = __fsub_rn(__fadd_rn(sn, sm), __fadd_rn(dot, dot));
        sq = fmaxf(sq, 0.0f);
        sBaseS[t & 3][t >> 2] = __fdiv_rn(__fsqrt_rn(sq), 0.2f);   // row = t
    }
    if (t < MT * KNN) {
        const int pair = t >> 3, k = t & 7;
        const float ax = sPm[pair][0] - sPn[0];
        const float ay = sPm[pair][1] - sPn[1];
        const float az = sPm[pair][2] - sPn[2];
        const float rx = sRef[k][0], ry = sRef[k][1], rz = sRef[k][2];
        const float cx = ry * az - rz * ay;
        const float cy = rz * ax - rx * az;
        const float cz = rx * ay - ry * ax;
        const float sv = sqrtf(cx * cx + cy * cy + cz * cz);
        const float cv = rx * ax + ry * ay + rz * az;
        float ang;
        if (sv == 0.0f) ang = 0.0f;          // degenerate -> 0, NEVER pi (r12 fix)
        else            ang = atan2f(sv, cv);
        // row = 16 + k*16 + pair -> stripe = pair&3, idx = 4 + 4k + (pair>>2)
        sBaseS[pair & 3][4 + 4 * k + (pair >> 2)] = ang * 3.8197186342054885f;
    }
    __syncthreads();

    // ---- A tile fill: batch all 36 wave-uniform bases upfront (9x float4),
    //      then a pure-compute loop (no LDS reads inside) ----
    {
        float rbase[36];
#pragma unroll
        for (int q = 0; q < 9; ++q) {
            const float4 v = *(const float4*)&sBaseS[r0][q * 4];
            rbase[q * 4 + 0] = v.x; rbase[q * 4 + 1] = v.y;
            rbase[q * 4 + 2] = v.z; rbase[q * 4 + 3] = v.w;
        }
        const unsigned base0 = (unsigned)((i * 4) ^ (r0 << 4)) + (unsigned)r0 * 256;
        char* const wr0 = (char*)sA + base0;          // even it (row&7 == r0)
        char* const wr1 = (char*)sA + (base0 ^ 64u);  // odd it  (row&7 == r0+4)
#pragma unroll
        for (int it = 0; it < 36; ++it) {
            const float rev0 = rbase[it] * dv2;               // radians->revs folded
            const float rev  = rev0 - floorf(rev0);           // v_fract: [0,1) revs
            const float s = __builtin_amdgcn_sinf(rev);
            const float c = __builtin_amdgcn_cosf(rev);
            const unsigned int pack = __builtin_amdgcn_perm(
                __float_as_uint(c), __float_as_uint(s), 0x07060302u);
            char* const wp = (it & 1) ? wr1 : wr0;
            *(unsigned int*)(wp + it * 1024) = pack;          // row*256 = r0*256 + it*1024
        }
    }
    __syncthreads();

    // ---- MFMA GEMM: wave w owns g-tiles {2w, 2w+1}; A-frag read ONCE -------
    const int wid  = r0;
    const int lane = i;
    const int rlo  = lane & 15;     // A row within tile / B col (g)
    const int kseg = lane >> 4;     // k sub-segment

    const short8_t* wf = (const short8_t*)g_wfrag;
    short8_t wdb[2][4], wab[2][4];
#pragma unroll
    for (int gt = 0; gt < 2; ++gt) {
        const int gtile = wid * 2 + gt;
#pragma unroll
        for (int kt = 0; kt < 4; ++kt) {
            wdb[gt][kt] = wf[(gtile * 4 + kt) * 64 + lane];
            wab[gt][kt] = wf[((8 + gtile) * 4 + kt) * 64 + lane];
        }
    }

    const char* sAb = (const char*)sA;
    f32x4_t accd[2] = {{0.f,0.f,0.f,0.f}, {0.f,0.f,0.f,0.f}};
#pragma unroll
    for (int kt = 0; kt < 4; ++kt) {
        int byte = rlo * 256 + kt * 64 + kseg * 16;
        byte ^= (rlo & 7) << 4;
        const short8_t af = *(const short8_t*)(sAb + byte);
        accd[0] = __builtin_amdgcn_mfma_f32_16x16x32_bf16(af, wdb[0][kt], accd[0], 0, 0, 0);
        accd[1] = __builtin_amdgcn_mfma_f32_16x16x32_bf16(af, wdb[1][kt], accd[1], 0, 0, 0);
    }

    f32x4_t amax[2] = {{0.f,0.f,0.f,0.f}, {0.f,0.f,0.f,0.f}};
#pragma unroll
    for (int k = 0; k < KNN; ++k) {
        f32x4_t acc0 = {0.f,0.f,0.f,0.f};
        f32x4_t acc1 = {0.f,0.f,0.f,0.f};
        const int rowb = MT + k * 16 + rlo;
#pragma unroll
        for (int kt = 0; kt < 4; ++kt) {
            int byte = rowb * 256 + kt * 64 + kseg * 16;
            byte ^= (rowb & 7) << 4;
            const short8_t af = *(const short8_t*)(sAb + byte);
            acc0 = __builtin_amdgcn_mfma_f32_16x16x32_bf16(af, wab[0][kt], acc0, 0, 0, 0);
            acc1 = __builtin_amdgcn_mfma_f32_16x16x32_bf16(af, wab[1][kt], acc1, 0, 0, 0);
        }
        if (k == 0) { amax[0] = acc0; amax[1] = acc1; }
        else {
#pragma unroll
            for (int r = 0; r < 4; ++r) {
                amax[0][r] = fmaxf(amax[0][r], acc0[r]);
                amax[1][r] = fmaxf(amax[1][r], acc1[r]);
            }
        }
    }

    // ---- epilogue: C/D mapping col=lane&15 (g), row=(lane>>4)*4+reg (m) ----
#pragma unroll
    for (int gt = 0; gt < 2; ++gt) {
        const int g = (wid * 2 + gt) * 16 + rlo;
        const float bdv = bd[g];
        const float bav = ba[g];
#pragma unroll
        for (int r = 0; r < 4; ++r) {
            const int m = m0 + kseg * 4 + r;
            out[(n * N_PTS + m) * HID + g] = accd[gt][r] + bdv + amax[gt][r] + bav;
        }
    }
}

extern "C" void kernel_launch(void* const* d_in, const int* in_sizes, int n_in,
                              void* d_out, int out_size, void* d_ws, size_t ws_size,
                              hipStream_t stream) {
    (void)in_sizes; (void)n_in; (void)out_size; (void)d_ws; (void)ws_size;
    const float* points = (const float*)d_in[0];
    const float* Wd     = (const float*)d_in[1];
    const float* bd     = (const float*)d_in[2];
    const float* Wa     = (const float*)d_in[3];
    const float* ba     = (const float*)d_in[4];
    float* out = (float*)d_out;

    prep_kernel<<<N_PTS, 64, 0, stream>>>(points, Wd, Wa);

    dim3 grid(N_PTS / MT, N_PTS);
    main_kernel<<<grid, NTHREADS, 0, stream>>>(points, bd, ba, out);
}

// Round 23
// 107.962 us; speedup vs baseline: 1.3338x; 1.0429x over previous
//
#include <hip/hip_runtime.h>
#include <math.h>

#define N_PTS 512
#define HID 128
#define KNN 8
#define MT 16               // m's per tile
#define NTILES 4            // tiles per block (pipelined)
#define NTHREADS 256        // 4 waves; each wave covers 2 g-tiles
#define NROWS 144           // 16 d rows + 128 a rows per tile

typedef __attribute__((ext_vector_type(8))) short short8_t;   // 8 bf16 (4 VGPRs)
typedef __attribute__((ext_vector_type(4))) float f32x4_t;    // MFMA acc

__device__ float g_refv[N_PTS * KNN * 3];          // [n][k][xyz] neighbor ref vectors
__device__ unsigned short g_wfrag[2 * 8 * 4 * 64 * 8]; // [sel][gtile][ktile][lane][j] bf16 B-frags

__device__ __forceinline__ unsigned short f2bf(float f) {   // RNE f32->bf16
    const unsigned int u = __float_as_uint(f);
    return (unsigned short)((u + 0x7FFFu + ((u >> 16) & 1u)) >> 16);
}

// -------- prep: fused wave-kNN + wfrag (VERBATIM r18/r19/r22-PASS) ----------
__global__ void __launch_bounds__(64) prep_kernel(
    const float* __restrict__ points, const float* __restrict__ Wd,
    const float* __restrict__ Wa)
{
    __shared__ float spts[N_PTS * 3];
    const int lane = threadIdx.x;       // 0..63
    const int n = blockIdx.x;           // 0..511

    for (int i = lane; i < N_PTS * 3; i += 64) spts[i] = points[i];
    __syncthreads();

    {
        const int idx = n * 64 + lane;
        const int sel = idx >> 14;          // 0 = Wd, 1 = Wa
        const int rem = idx & 16383;
        const int gg = rem >> 7, kk = rem & 127;
        const int gtile = gg >> 4, glo = gg & 15;
        const int ktile = kk >> 5, kmid = (kk >> 3) & 3, j = kk & 7;
        const int fl = kmid * 16 + glo;
        const int dst = ((((sel * 8 + gtile) * 4 + ktile) * 64) + fl) * 8 + j;
        const float v = sel ? Wa[gg * HID + kk] : Wd[gg * HID + kk];
        g_wfrag[dst] = f2bf(v);
    }

    const float px = spts[n * 3 + 0], py = spts[n * 3 + 1], pz = spts[n * 3 + 2];
    unsigned long long keys[8];
#pragma unroll
    for (int j = 0; j < 8; ++j) {
        const int m = lane * 8 + j;
        const float dx = spts[m * 3 + 0] - px;
        const float dy = spts[m * 3 + 1] - py;
        const float dz = spts[m * 3 + 2] - pz;
        const float sq = dx * dx + dy * dy + dz * dz;
        keys[j] = ((unsigned long long)__float_as_uint(sq) << 32) | (unsigned)m;
    }
    for (int r = 0; r < 9; ++r) {
        unsigned long long lmin = ~0ULL;
#pragma unroll
        for (int j = 0; j < 8; ++j) lmin = keys[j] < lmin ? keys[j] : lmin;
        for (int s = 1; s < 64; s <<= 1) {
            const unsigned long long o = __shfl_xor(lmin, s, 64);
            lmin = o < lmin ? o : lmin;
        }
        const int mwin = (int)(unsigned)lmin;
        if ((mwin >> 3) == lane) keys[mwin & 7] = ~0ULL;
        if (r > 0 && lane == 0) {
            const int k = r - 1;
            g_refv[(n * KNN + k) * 3 + 0] = __fsub_rn(spts[mwin * 3 + 0], px);
            g_refv[(n * KNN + k) * 3 + 1] = __fsub_rn(spts[mwin * 3 + 1], py);
            g_refv[(n * KNN + k) * 3 + 2] = __fsub_rn(spts[mwin * 3 + 2], pz);
        }
    }
}

// -------- main: 4-tile pipeline, dbuf LDS, fused fill(t+1) || gemm(t) -------
__global__ void __launch_bounds__(NTHREADS, 2) main_kernel(
    const float* __restrict__ points, const float* __restrict__ bd,
    const float* __restrict__ ba, float* __restrict__ out)
{
    __shared__ __align__(16) unsigned short sA[2][NROWS * HID];  // 2 x 36 KB
    __shared__ __align__(16) float sBaseS[NTILES][4][36];  // stripe-major bases
    __shared__ float sRef[KNN][3];
    __shared__ float sPm[MT * NTILES][3];
    __shared__ float sPn[3];

    const int t = threadIdx.x;
    const int n = blockIdx.y;
    const int M0 = blockIdx.x * (MT * NTILES);

    const int r0 = t >> 6;              // wave id (0..3) = row stripe
    const int i  = t & 63;              // frequency index (= lane)
    const float dv2 = expf(-0.14391156831212787f * (float)i) * 0.15915494309189535f;

    // B-frags hoisted: LDS caps occupancy at 2 blocks/CU, so VGPRs are free
    const int wid = r0, lane = i;
    const short8_t* wf = (const short8_t*)g_wfrag;
    short8_t wdb[2][4], wab[2][4];
#pragma unroll
    for (int gt = 0; gt < 2; ++gt) {
        const int gtile = wid * 2 + gt;
#pragma unroll
        for (int kt = 0; kt < 4; ++kt) {
            wdb[gt][kt] = wf[(gtile * 4 + kt) * 64 + lane];
            wab[gt][kt] = wf[((8 + gtile) * 4 + kt) * 64 + lane];
        }
    }

    // ---- stage small data ----
    if (t < 3) sPn[t] = points[n * 3 + t];
    if (t >= 8 && t < 8 + KNN * 3) { int q = t - 8; sRef[q / 3][q % 3] = g_refv[n * KNN * 3 + q]; }
    if (t >= 64 && t < 64 + MT * NTILES * 3) { int q = t - 64; sPm[q / 3][q % 3] = points[M0 * 3 + q]; }
    __syncthreads();

    // ---- geometry for ALL tiles (r12-validated arithmetic) ----
    if (t < MT * NTILES) {              // 64 d-indices; t = tt*16 + pair
        const int tt = t >> 4, pair = t & 15;
        const float qx = sPm[t][0], qy = sPm[t][1], qz = sPm[t][2];
        const float sn = __fadd_rn(__fadd_rn(__fmul_rn(sPn[0], sPn[0]), __fmul_rn(sPn[1], sPn[1])), __fmul_rn(sPn[2], sPn[2]));
        const float sm = __fadd_rn(__fadd_rn(__fmul_rn(qx, qx), __fmul_rn(qy, qy)), __fmul_rn(qz, qz));
        float dot = __fmul_rn(sPn[0], qx);
        dot = fmaf(sPn[1], qy, dot);
        dot = fmaf(sPn[2], qz, dot);
        float sq = __fsub_rn(__fadd_rn(sn, sm), __fadd_rn(dot, dot));
        sq = fmaxf(sq, 0.0f);
        sBaseS[tt][pair & 3][pair >> 2] = __fdiv_rn(__fsqrt_rn(sq), 0.2f);
    }
#pragma unroll
    for (int q2 = 0; q2 < 2; ++q2) {    // 512 a-indices, 2 per thread
        const int idx = q2 * 256 + t;
        const int tt = idx >> 7, rem = idx & 127, pair = rem >> 3, k = rem & 7;
        const int mp = tt * MT + pair;
        const float ax = sPm[mp][0] - sPn[0];
        const float ay = sPm[mp][1] - sPn[1];
        const float az = sPm[mp][2] - sPn[2];
        const float rx = sRef[k][0], ry = sRef[k][1], rz = sRef[k][2];
        const float cx = ry * az - rz * ay;
        const float cy = rz * ax - rx * az;
        const float cz = rx * ay - ry * ax;
        const float sv = sqrtf(cx * cx + cy * cy + cz * cz);
        const float cv = rx * ax + ry * ay + rz * az;
        float ang;
        if (sv == 0.0f) ang = 0.0f;          // degenerate -> 0, NEVER pi (r12 fix)
        else            ang = atan2f(sv, cv);
        sBaseS[tt][pair & 3][4 + 4 * k + (pair >> 2)] = ang * 3.8197186342054885f;
    }
    __syncthreads();

    const unsigned base0 = (unsigned)((i * 4) ^ (r0 << 4)) + (unsigned)r0 * 256;
    const int rlo  = lane & 15;
    const int kseg = lane >> 4;

    // ---- prologue: fill tile 0 into sA[0] (r22 fill, verbatim values) ----
    {
        float rbase[36];
#pragma unroll
        for (int q = 0; q < 9; ++q) {
            const float4 v = *(const float4*)&sBaseS[0][r0][q * 4];
            rbase[q * 4 + 0] = v.x; rbase[q * 4 + 1] = v.y;
            rbase[q * 4 + 2] = v.z; rbase[q * 4 + 3] = v.w;
        }
        char* const wr0 = (char*)sA[0] + base0;
        char* const wr1 = (char*)sA[0] + (base0 ^ 64u);
#pragma unroll
        for (int it = 0; it < 36; ++it) {
            const float rev0 = rbase[it] * dv2;
            const float rev  = rev0 - floorf(rev0);
            const float s = __builtin_amdgcn_sinf(rev);
            const float c = __builtin_amdgcn_cosf(rev);
            const unsigned int pack = __builtin_amdgcn_perm(
                __float_as_uint(c), __float_as_uint(s), 0x07060302u);
            char* const wp = (it & 1) ? wr1 : wr0;
            *(unsigned int*)(wp + it * 1024) = pack;
        }
    }
    __syncthreads();

    // ---- phases: gemm(tile tt from sA[tt&1]) fused with fill(tt+1 -> sA[~tt&1]) ----
    const f32x4_t vz = {0.f, 0.f, 0.f, 0.f};
#pragma unroll
    for (int tt = 0; tt < NTILES; ++tt) {
        const char* sAb = (const char*)sA[tt & 1];
        const bool dofill = (tt < NTILES - 1);

        float rbase[36];
        char* wr0 = (char*)sA[(tt + 1) & 1] + base0;
        char* wr1 = (char*)sA[(tt + 1) & 1] + (base0 ^ 64u);
        if (dofill) {
#pragma unroll
            for (int q = 0; q < 9; ++q) {
                const float4 v = *(const float4*)&sBaseS[tt + 1][r0][q * 4];
                rbase[q * 4 + 0] = v.x; rbase[q * 4 + 1] = v.y;
                rbase[q * 4 + 2] = v.z; rbase[q * 4 + 3] = v.w;
            }
        }

        f32x4_t accd[2] = {vz, vz};
        f32x4_t amax[2] = {vz, vz};
        f32x4_t acc0 = vz, acc1 = vz;

#pragma unroll
        for (int it = 0; it < 36; ++it) {
            // --- fill one element of tile tt+1 (VALU + trans pipe) ---
            if (dofill) {
                const float rev0 = rbase[it] * dv2;
                const float rev  = rev0 - floorf(rev0);
                const float s = __builtin_amdgcn_sinf(rev);
                const float c = __builtin_amdgcn_cosf(rev);
                const unsigned int pack = __builtin_amdgcn_perm(
                    __float_as_uint(c), __float_as_uint(s), 0x07060302u);
                char* const wp = (it & 1) ? wr1 : wr0;
                *(unsigned int*)(wp + it * 1024) = pack;
            }
            // --- 2 MFMAs of tile tt (MFMA pipe) ---
            if (it < 4) {
                const int kt = it;
                int byte = rlo * 256 + kt * 64 + kseg * 16;
                byte ^= (rlo & 7) << 4;
                const short8_t af = *(const short8_t*)(sAb + byte);
                accd[0] = __builtin_amdgcn_mfma_f32_16x16x32_bf16(af, wdb[0][kt], accd[0], 0, 0, 0);
                accd[1] = __builtin_amdgcn_mfma_f32_16x16x32_bf16(af, wdb[1][kt], accd[1], 0, 0, 0);
            } else {
                const int q = it - 4, k = q >> 2, kt = q & 3;
                const int rowb = MT + k * 16 + rlo;
                int byte = rowb * 256 + kt * 64 + kseg * 16;
                byte ^= (rowb & 7) << 4;
                const short8_t af = *(const short8_t*)(sAb + byte);
                acc0 = __builtin_amdgcn_mfma_f32_16x16x32_bf16(af, wab[0][kt], acc0, 0, 0, 0);
                acc1 = __builtin_amdgcn_mfma_f32_16x16x32_bf16(af, wab[1][kt], acc1, 0, 0, 0);
                if (kt == 3) {
                    if (k == 0) { amax[0] = acc0; amax[1] = acc1; }
                    else {
#pragma unroll
                        for (int r = 0; r < 4; ++r) {
                            amax[0][r] = fmaxf(amax[0][r], acc0[r]);
                            amax[1][r] = fmaxf(amax[1][r], acc1[r]);
                        }
                    }
                    acc0 = vz; acc1 = vz;
                }
            }
        }

        // ---- epilogue for tile tt ----
#pragma unroll
        for (int gt = 0; gt < 2; ++gt) {
            const int g = (wid * 2 + gt) * 16 + rlo;
            const float bdv = bd[g];
            const float bav = ba[g];
#pragma unroll
            for (int r = 0; r < 4; ++r) {
                const int m = M0 + tt * MT + kseg * 4 + r;
                out[(n * N_PTS + m) * HID + g] = accd[gt][r] + bdv + amax[gt][r] + bav;
            }
        }
        __syncthreads();
    }
}

extern "C" void kernel_launch(void* const* d_in, const int* in_sizes, int n_in,
                              void* d_out, int out_size, void* d_ws, size_t ws_size,
                              hipStream_t stream) {
    (void)in_sizes; (void)n_in; (void)out_size; (void)d_ws; (void)ws_size;
    const float* points = (const float*)d_in[0];
    const float* Wd     = (const float*)d_in[1];
    const float* bd     = (const float*)d_in[2];
    const float* Wa     = (const float*)d_in[3];
    const float* ba     = (const float*)d_in[4];
    float* out = (float*)d_out;

    prep_kernel<<<N_PTS, 64, 0, stream>>>(points, Wd, Wa);

    dim3 grid(N_PTS / (MT * NTILES), N_PTS);
    main_kernel<<<grid, NTHREADS, 0, stream>>>(points, bd, ba, out);
}